// Round 1
// baseline (382.110 us; speedup 1.0000x reference)
//
#include <hip/hip_runtime.h>
#include <math.h>

#define G 20
#define N1 400      // nodes
#define N2 760      // edges
#define CTXS 64
#define HID 640
#define NB 256      // batch
#define ITERS 100
#define PI_D 3.14159265358979323846

// One block per batch item. All Dykstra state in LDS.
// pinv(L) applied exactly via 2D DCT eigendecomposition of the grid Laplacian.
__global__ __launch_bounds__(256, 1) void spnet_kernel(
    const float* __restrict__ dmat, const float* __restrict__ W1,
    const float* __restrict__ b1v, const float* __restrict__ W2,
    const float* __restrict__ b2v, const float* __restrict__ beq,
    float* __restrict__ out)
{
  const int tid = threadIdx.x;
  const int bb  = blockIdx.x;

  __shared__ float sy[N2], sq[N2], st[N2];       // Dykstra state (p fused into st)
  __shared__ float sr[N1], sc1[N1], sc2[N1], sd1[N1];  // resid / DCT temps; sr reused for z
  __shared__ float sV[N1];     // V[k*20+i] = eigvec row k
  __shared__ float sS[N1];     // 1/(lam_k+lam_l), entry 0 = 0 (null mode)
  __shared__ float sbeq[N1];
  __shared__ float sh[HID];
  __shared__ float sdrow[CTXS];
  __shared__ int   eu[N2], ev[N2];               // edge endpoints
  __shared__ int   gOR[N1], gOD[N1], gIR[N1], gID[N1];  // node->incident edge idx (-1 = none)

  // ---------- init constant tables ----------
  for (int t = tid; t < N1; t += 256) {
    int k = t / G, i = t - G * k;
    double nk = (k == 0) ? 0.22360679774997896 : 0.31622776601683794; // 1/sqrt(20), sqrt(0.1)
    sV[t] = (float)(nk * cos(PI_D * (double)(k * (2 * i + 1)) / 40.0));
    double lk = 2.0 - 2.0 * cos(PI_D * (double)k / 20.0);
    double ll = 2.0 - 2.0 * cos(PI_D * (double)i / 20.0);
    sS[t] = (t == 0) ? 0.f : (float)(1.0 / (lk + ll));
    int ii = k, jj = i;  // node (ii,jj), u = ii*20+jj
    gOR[t] = (jj < 19) ? ((ii < 19) ? 39 * ii + 2 * jj       : 741 + jj)       : -1;
    gOD[t] = (ii < 19) ? (39 * ii + ((jj < 19) ? 2 * jj + 1 : 38))             : -1;
    gIR[t] = (jj > 0)  ? ((ii < 19) ? 39 * ii + 2 * (jj - 1) : 741 + (jj - 1)) : -1;
    gID[t] = (ii > 0)  ? (39 * (ii - 1) + ((jj < 19) ? 2 * jj + 1 : 38))       : -1;
    sbeq[t] = beq[t];
  }
  for (int t = tid; t < N2; t += 256) {
    int u, v;
    if (t < 741) {
      int i = t / 39, rem = t - 39 * i;
      if (rem < 38) {
        int j = rem >> 1;
        u = i * G + j;
        v = (rem & 1) ? (u + G) : (u + 1);
      } else { u = i * G + 19; v = u + G; }
    } else { u = 380 + (t - 741); v = u + 1; }
    eu[t] = u; ev[t] = v;
  }
  if (tid < CTXS) sdrow[tid] = dmat[bb * CTXS + tid];
  __syncthreads();

  // ---------- layer 1: h = leaky(d @ W1 + b1) ----------
  {
    int o0 = tid, o1 = tid + 256, o2 = tid + 512;
    int o2c = (o2 < HID) ? o2 : 0;
    float a0 = b1v[o0], a1 = b1v[o1], a2 = b1v[o2c];
#pragma unroll 8
    for (int k = 0; k < CTXS; ++k) {
      float hk = sdrow[k];
      const float* w = W1 + k * HID;
      a0 = fmaf(hk, w[o0], a0);
      a1 = fmaf(hk, w[o1], a1);
      a2 = fmaf(hk, w[o2c], a2);
    }
    sh[o0] = (a0 > 0.f) ? a0 : 0.1f * a0;
    sh[o1] = (a1 > 0.f) ? a1 : 0.1f * a1;
    if (o2 < HID) sh[o2] = (a2 > 0.f) ? a2 : 0.1f * a2;
  }
  __syncthreads();

  // ---------- layer 2: w = h @ W2 + b2 ; y0 = -w, q0 = 0, t0 = y0 + p0 = y0 ----------
  {
    int e0 = tid, e1 = tid + 256, e2 = tid + 512;
    int e2c = (e2 < N2) ? e2 : 0;
    float a0 = b2v[e0], a1 = b2v[e1], a2 = b2v[e2c];
#pragma unroll 4
    for (int k = 0; k < HID; ++k) {
      float hk = sh[k];
      const float* w = W2 + k * N2;
      a0 = fmaf(hk, w[e0], a0);
      a1 = fmaf(hk, w[e1], a1);
      a2 = fmaf(hk, w[e2c], a2);
    }
    sy[e0] = -a0; st[e0] = -a0; sq[e0] = 0.f;
    sy[e1] = -a1; st[e1] = -a1; sq[e1] = 0.f;
    if (e2 < N2) { sy[e2] = -a2; st[e2] = -a2; sq[e2] = 0.f; }
  }
  __syncthreads();

  // stage output indices (loop-invariant): out idx tid -> (ka,kc); tid+256 -> (ka2,kc2)
  const int ka  = tid / G,        kc  = tid - G * ka;
  const int t2i = tid + 256;
  const bool has2 = (t2i < N1);   // tid < 144
  const int ka2 = t2i / G,        kc2 = t2i - G * ka2;

  // ---------- 100 Dykstra iterations ----------
  for (int it = 0; it < ITERS; ++it) {
    // resid[u] = (t @ A^T - b_eq)[u]  (sparse gather, st holds t = y + p)
    for (int u = tid; u < N1; u += 256) {
      float r = -sbeq[u];
      int x;
      x = gOR[u]; if (x >= 0) r += st[x];
      x = gOD[u]; if (x >= 0) r += st[x];
      x = gIR[u]; if (x >= 0) r -= st[x];
      x = gID[u]; if (x >= 0) r -= st[x];
      sr[u] = r;
    }
    __syncthreads();

    // z = pinv(L) @ resid via 2D DCT:  C = V R V^T ; C *= S ; Z = V^T C V
    // stage 1: c1[k][j] = sum_i V[k][i] r[i][j]
    {
      float acc = 0.f;
#pragma unroll
      for (int m = 0; m < G; ++m) acc = fmaf(sV[ka * G + m], sr[m * G + kc], acc);
      sc1[tid] = acc;
      if (has2) {
        float a2 = 0.f;
#pragma unroll
        for (int m = 0; m < G; ++m) a2 = fmaf(sV[ka2 * G + m], sr[m * G + kc2], a2);
        sc1[t2i] = a2;
      }
    }
    __syncthreads();
    // stage 2: c2[k][l] = (sum_j c1[k][j] V[l][j]) * S[k][l]
    {
      float acc = 0.f;
#pragma unroll
      for (int m = 0; m < G; ++m) acc = fmaf(sc1[ka * G + m], sV[kc * G + m], acc);
      sc2[tid] = acc * sS[tid];
      if (has2) {
        float a2 = 0.f;
#pragma unroll
        for (int m = 0; m < G; ++m) a2 = fmaf(sc1[ka2 * G + m], sV[kc2 * G + m], a2);
        sc2[t2i] = a2 * sS[t2i];
      }
    }
    __syncthreads();
    // stage 3: d1[i][l] = sum_k V[k][i] c2[k][l]
    {
      float acc = 0.f;
#pragma unroll
      for (int m = 0; m < G; ++m) acc = fmaf(sV[m * G + ka], sc2[m * G + kc], acc);
      sd1[tid] = acc;
      if (has2) {
        float a2 = 0.f;
#pragma unroll
        for (int m = 0; m < G; ++m) a2 = fmaf(sV[m * G + ka2], sc2[m * G + kc2], a2);
        sd1[t2i] = a2;
      }
    }
    __syncthreads();
    // stage 4: z[i][j] = sum_l d1[i][l] V[l][j]   (store into sr)
    {
      float acc = 0.f;
#pragma unroll
      for (int m = 0; m < G; ++m) acc = fmaf(sd1[ka * G + m], sV[m * G + kc], acc);
      sr[tid] = acc;
      if (has2) {
        float a2 = 0.f;
#pragma unroll
      for (int m = 0; m < G; ++m) a2 = fmaf(sd1[ka2 * G + m], sV[m * G + kc2], a2);
        sr[t2i] = a2;
      }
    }
    __syncthreads();

    // edge update: yp = t - (z@A);  p' = t-yp;  t2 = yp+q;  y = max(t2,0);
    // q' = t2-y;  t_next = y + p'   (fuses next iteration's t = y + p)
    for (int e = tid; e < N2; e += 256) {
      float t  = st[e];
      float yp = t - (sr[eu[e]] - sr[ev[e]]);
      float pn = t - yp;
      float t2 = yp + sq[e];
      float yn = fmaxf(t2, 0.f);
      sy[e] = yn;
      sq[e] = t2 - yn;
      st[e] = yn + pn;
    }
    __syncthreads();
  }

  for (int e = tid; e < N2; e += 256) out[bb * N2 + e] = sy[e];
}

extern "C" void kernel_launch(void* const* d_in, const int* in_sizes, int n_in,
                              void* d_out, int out_size, void* d_ws, size_t ws_size,
                              hipStream_t stream) {
  const float* d   = (const float*)d_in[0];
  const float* W1  = (const float*)d_in[1];
  const float* b1  = (const float*)d_in[2];
  const float* W2  = (const float*)d_in[3];
  const float* b2  = (const float*)d_in[4];
  // d_in[5] = A (structure hardcoded), d_in[6] = b_eq
  const float* beq = (const float*)d_in[6];
  float* out = (float*)d_out;
  spnet_kernel<<<NB, 256, 0, stream>>>(d, W1, b1, W2, b2, beq, out);
}

// Round 2
// 224.593 us; speedup vs baseline: 1.7013x; 1.7013x over previous
//
#include <hip/hip_runtime.h>
#include <math.h>

#define G 20
#define N1 400      // nodes
#define N2 760      // edges
#define CTXS 64
#define HID 640
#define NB 256      // batch
#define ITERS 100
#define PI_D 3.14159265358979323846

// One block per batch item. Dykstra state (t,q,y) in registers (3 edges/thread).
// DCT eigenbasis V register-cached per thread (pair mapping (a,b)+(b,a), 210 threads).
// All stage data reads are row-contiguous ds_read_b128 via transposed layouts.
__global__ __launch_bounds__(256, 1) void spnet_kernel(
    const float* __restrict__ dmat, const float* __restrict__ W1,
    const float* __restrict__ b1v, const float* __restrict__ W2,
    const float* __restrict__ b2v, const float* __restrict__ beq,
    float* __restrict__ out)
{
  const int tid = threadIdx.x;
  const int bb  = blockIdx.x;

  __shared__ __align__(16) float sV[N1];      // V[k*20+i], init only
  __shared__ __align__(16) float sdrow[CTXS];
  __shared__ __align__(16) float sh[HID];
  __shared__ __align__(16) float st[N2 + 4];  // t edge vector; st[760..763]=0 sentinel
  __shared__ __align__(16) float srT[N1];     // resid transposed: srT[j*20+i] = r[i*20+j]
  __shared__ __align__(16) float sc1[N1];     // c1[k*20+j] = (V R)
  __shared__ __align__(16) float sc2T[N1];    // c2 transposed: sc2T[l*20+k]
  __shared__ __align__(16) float sd1[N1];     // d1[i*20+l] = (V^T c2)
  __shared__ __align__(16) float sz[N1];      // z[i*20+j]

  // ---------- init V table ----------
  for (int t = tid; t < N1; t += 256) {
    int k = t / G, i = t - G * k;
    double nk = (k == 0) ? 0.22360679774997896 : 0.31622776601683794; // 1/sqrt20, sqrt(.1)
    sV[t] = (float)(nk * cos(PI_D * (double)(k * (2 * i + 1)) / 40.0));
  }
  if (tid < CTXS) sdrow[tid] = dmat[bb * CTXS + tid];
  if (tid == 0) { st[N2] = 0.f; st[N2 + 1] = 0.f; st[N2 + 2] = 0.f; st[N2 + 3] = 0.f; }
  __syncthreads();

  // ---------- MLP layer 1: h = leaky(d @ W1 + b1), float4 ----------
  if (tid < HID / 4) {
    float4 acc = *(const float4*)(b1v + 4 * tid);
#pragma unroll 4
    for (int k = 0; k < CTXS; k += 4) {
      float4 h4 = *(const float4*)(sdrow + k);
      const float* wb = W1 + k * HID + 4 * tid;
      float4 w0 = *(const float4*)(wb);
      float4 w1 = *(const float4*)(wb + HID);
      float4 w2 = *(const float4*)(wb + 2 * HID);
      float4 w3 = *(const float4*)(wb + 3 * HID);
      acc.x = fmaf(h4.x, w0.x, acc.x); acc.y = fmaf(h4.x, w0.y, acc.y);
      acc.z = fmaf(h4.x, w0.z, acc.z); acc.w = fmaf(h4.x, w0.w, acc.w);
      acc.x = fmaf(h4.y, w1.x, acc.x); acc.y = fmaf(h4.y, w1.y, acc.y);
      acc.z = fmaf(h4.y, w1.z, acc.z); acc.w = fmaf(h4.y, w1.w, acc.w);
      acc.x = fmaf(h4.z, w2.x, acc.x); acc.y = fmaf(h4.z, w2.y, acc.y);
      acc.z = fmaf(h4.z, w2.z, acc.z); acc.w = fmaf(h4.z, w2.w, acc.w);
      acc.x = fmaf(h4.w, w3.x, acc.x); acc.y = fmaf(h4.w, w3.y, acc.y);
      acc.z = fmaf(h4.w, w3.z, acc.z); acc.w = fmaf(h4.w, w3.w, acc.w);
    }
    acc.x = acc.x > 0.f ? acc.x : 0.1f * acc.x;
    acc.y = acc.y > 0.f ? acc.y : 0.1f * acc.y;
    acc.z = acc.z > 0.f ? acc.z : 0.1f * acc.z;
    acc.w = acc.w > 0.f ? acc.w : 0.1f * acc.w;
    *(float4*)(sh + 4 * tid) = acc;
  }
  __syncthreads();

  // ---------- MLP layer 2: w = h @ W2 + b2 ; st = t0 = -w ----------
  if (tid < N2 / 4) {
    float4 acc = *(const float4*)(b2v + 4 * tid);
#pragma unroll 2
    for (int k = 0; k < HID; k += 4) {
      float4 h4 = *(const float4*)(sh + k);
      const float* wb = W2 + k * N2 + 4 * tid;
      float4 w0 = *(const float4*)(wb);
      float4 w1 = *(const float4*)(wb + N2);
      float4 w2 = *(const float4*)(wb + 2 * N2);
      float4 w3 = *(const float4*)(wb + 3 * N2);
      acc.x = fmaf(h4.x, w0.x, acc.x); acc.y = fmaf(h4.x, w0.y, acc.y);
      acc.z = fmaf(h4.x, w0.z, acc.z); acc.w = fmaf(h4.x, w0.w, acc.w);
      acc.x = fmaf(h4.y, w1.x, acc.x); acc.y = fmaf(h4.y, w1.y, acc.y);
      acc.z = fmaf(h4.y, w1.z, acc.z); acc.w = fmaf(h4.y, w1.w, acc.w);
      acc.x = fmaf(h4.z, w2.x, acc.x); acc.y = fmaf(h4.z, w2.y, acc.y);
      acc.z = fmaf(h4.z, w2.z, acc.z); acc.w = fmaf(h4.z, w2.w, acc.w);
      acc.x = fmaf(h4.w, w3.x, acc.x); acc.y = fmaf(h4.w, w3.y, acc.y);
      acc.z = fmaf(h4.w, w3.z, acc.z); acc.w = fmaf(h4.w, w3.w, acc.w);
    }
    float4 s; s.x = -acc.x; s.y = -acc.y; s.z = -acc.z; s.w = -acc.w;
    *(float4*)(st + 4 * tid) = s;
  }
  __syncthreads();

  // ---------- per-thread register state ----------
  // Edge ownership: edges tid, tid+256, tid+512
  int eu_r[3], ev_r[3];
  float t_r[3], q_r[3], y_r[3];
#pragma unroll
  for (int j = 0; j < 3; ++j) {
    int e = tid + 256 * j;
    int u = 0, v = 0;
    if (e < N2) {
      if (e < 741) {
        int i = e / 39, rem = e - 39 * i;
        if (rem < 38) { int jj = rem >> 1; u = i * G + jj; v = (rem & 1) ? (u + G) : (u + 1); }
        else { u = i * G + 19; v = u + G; }
      } else { u = 380 + (e - 741); v = u + 1; }
    }
    eu_r[j] = u; ev_r[j] = v;
    q_r[j] = 0.f; y_r[j] = 0.f;
    t_r[j] = (e < N2) ? st[e] : 0.f;
  }

  // Node ownership: nodes tid and tid+256 (tid<144). -1 edges -> sentinel N2.
  int oA0, oA1, iA0, iA1, tpA; float bqA;
  {
    int u = tid, ii = u / G, jj = u - G * ii;
    oA0 = (jj < 19) ? ((ii < 19) ? 39 * ii + 2 * jj       : 741 + jj)       : N2;
    oA1 = (ii < 19) ? (39 * ii + ((jj < 19) ? 2 * jj + 1 : 38))             : N2;
    iA0 = (jj > 0)  ? ((ii < 19) ? 39 * ii + 2 * (jj - 1) : 741 + (jj - 1)) : N2;
    iA1 = (ii > 0)  ? (39 * (ii - 1) + ((jj < 19) ? 2 * jj + 1 : 38))       : N2;
    tpA = jj * G + ii;
    bqA = beq[u];
  }
  const bool hasB = (tid < 144);
  int oB0 = N2, oB1 = N2, iB0 = N2, iB1 = N2, tpB = 0; float bqB = 0.f;
  if (hasB) {
    int u = tid + 256, ii = u / G, jj = u - G * ii;
    oB0 = (jj < 19) ? ((ii < 19) ? 39 * ii + 2 * jj       : 741 + jj)       : N2;
    oB1 = (ii < 19) ? (39 * ii + ((jj < 19) ? 2 * jj + 1 : 38))             : N2;
    iB0 = (jj > 0)  ? ((ii < 19) ? 39 * ii + 2 * (jj - 1) : 741 + (jj - 1)) : N2;
    iB1 = (ii > 0)  ? (39 * (ii - 1) + ((jj < 19) ? 2 * jj + 1 : 38))       : N2;
    tpB = jj * G + ii;
    bqB = beq[u];
  }

  // DCT pair ownership: tid<210 -> (a,b), a<=b; handles outputs (a,b) and (b,a).
  const bool hasP = (tid < 210);
  int a = 0, b = 0;
  float Vra[G], Vrb[G], Vca[G], Vcb[G];
  float Sab = 0.f;
  if (hasP) {
    int r = tid;
    while (r >= G - a) { r -= G - a; ++a; }
    b = a + r;
#pragma unroll
    for (int m = 0; m < G; ++m) {
      Vra[m] = sV[a * G + m]; Vrb[m] = sV[b * G + m];
      Vca[m] = sV[m * G + a]; Vcb[m] = sV[m * G + b];
    }
    double la = 2.0 - 2.0 * cos(PI_D * (double)a / 20.0);
    double lb = 2.0 - 2.0 * cos(PI_D * (double)b / 20.0);
    Sab = (a == 0 && b == 0) ? 0.f : (float)(1.0 / (la + lb));
  }
  const float4* rowA4[4]; // stage row pointers (constant across iters)
  const float4* rowB4[4];
  rowA4[0] = (const float4*)(srT + b * G);  rowB4[0] = (const float4*)(srT + a * G);
  rowA4[1] = (const float4*)(sc1 + a * G);  rowB4[1] = (const float4*)(sc1 + b * G);
  rowA4[2] = (const float4*)(sc2T + b * G); rowB4[2] = (const float4*)(sc2T + a * G);
  rowA4[3] = (const float4*)(sd1 + a * G);  rowB4[3] = (const float4*)(sd1 + b * G);

  // ---------- 100 Dykstra iterations ----------
  for (int it = 0; it < ITERS; ++it) {
    // node: resid (transposed store)
    {
      float rA = (st[oA0] + st[oA1]) - (st[iA0] + st[iA1]) - bqA;
      srT[tpA] = rA;
      if (hasB) {
        float rB = (st[oB0] + st[oB1]) - (st[iB0] + st[iB1]) - bqB;
        srT[tpB] = rB;
      }
    }
    __syncthreads();

    // stage1: c1[x][y] = sum_i V[x][i] R[i][y]   (reads srT rows, b128)
    if (hasP) {
      float x0 = 0.f, x1 = 0.f;
#pragma unroll
      for (int m = 0; m < 5; ++m) {
        float4 ta = rowA4[0][m], tb = rowB4[0][m];
        x0 = fmaf(Vra[4 * m], ta.x, x0); x0 = fmaf(Vra[4 * m + 1], ta.y, x0);
        x0 = fmaf(Vra[4 * m + 2], ta.z, x0); x0 = fmaf(Vra[4 * m + 3], ta.w, x0);
        x1 = fmaf(Vrb[4 * m], tb.x, x1); x1 = fmaf(Vrb[4 * m + 1], tb.y, x1);
        x1 = fmaf(Vrb[4 * m + 2], tb.z, x1); x1 = fmaf(Vrb[4 * m + 3], tb.w, x1);
      }
      sc1[a * G + b] = x0; sc1[b * G + a] = x1;
    }
    __syncthreads();

    // stage2: c2[x][y] = S * sum_m c1[x][m] V[y][m]  (write transposed)
    if (hasP) {
      float x0 = 0.f, x1 = 0.f;
#pragma unroll
      for (int m = 0; m < 5; ++m) {
        float4 ta = rowA4[1][m], tb = rowB4[1][m];
        x0 = fmaf(Vrb[4 * m], ta.x, x0); x0 = fmaf(Vrb[4 * m + 1], ta.y, x0);
        x0 = fmaf(Vrb[4 * m + 2], ta.z, x0); x0 = fmaf(Vrb[4 * m + 3], ta.w, x0);
        x1 = fmaf(Vra[4 * m], tb.x, x1); x1 = fmaf(Vra[4 * m + 1], tb.y, x1);
        x1 = fmaf(Vra[4 * m + 2], tb.z, x1); x1 = fmaf(Vra[4 * m + 3], tb.w, x1);
      }
      sc2T[b * G + a] = x0 * Sab; sc2T[a * G + b] = x1 * Sab;
    }
    __syncthreads();

    // stage3: d1[x][y] = sum_k V[k][x] c2T[y][k]
    if (hasP) {
      float x0 = 0.f, x1 = 0.f;
#pragma unroll
      for (int m = 0; m < 5; ++m) {
        float4 ta = rowA4[2][m], tb = rowB4[2][m];
        x0 = fmaf(Vca[4 * m], ta.x, x0); x0 = fmaf(Vca[4 * m + 1], ta.y, x0);
        x0 = fmaf(Vca[4 * m + 2], ta.z, x0); x0 = fmaf(Vca[4 * m + 3], ta.w, x0);
        x1 = fmaf(Vcb[4 * m], tb.x, x1); x1 = fmaf(Vcb[4 * m + 1], tb.y, x1);
        x1 = fmaf(Vcb[4 * m + 2], tb.z, x1); x1 = fmaf(Vcb[4 * m + 3], tb.w, x1);
      }
      sd1[a * G + b] = x0; sd1[b * G + a] = x1;
    }
    __syncthreads();

    // stage4: z[x][y] = sum_l d1[x][l] V[l][y]
    if (hasP) {
      float x0 = 0.f, x1 = 0.f;
#pragma unroll
      for (int m = 0; m < 5; ++m) {
        float4 ta = rowA4[3][m], tb = rowB4[3][m];
        x0 = fmaf(Vcb[4 * m], ta.x, x0); x0 = fmaf(Vcb[4 * m + 1], ta.y, x0);
        x0 = fmaf(Vcb[4 * m + 2], ta.z, x0); x0 = fmaf(Vcb[4 * m + 3], ta.w, x0);
        x1 = fmaf(Vca[4 * m], tb.x, x1); x1 = fmaf(Vca[4 * m + 1], tb.y, x1);
        x1 = fmaf(Vca[4 * m + 2], tb.z, x1); x1 = fmaf(Vca[4 * m + 3], tb.w, x1);
      }
      sz[a * G + b] = x0; sz[b * G + a] = x1;
    }
    __syncthreads();

    // edge: register-resident Dykstra state; pn = p' = (zA)_e = z_u - z_v
#pragma unroll
    for (int j = 0; j < 3; ++j) {
      int e = tid + 256 * j;
      if (e < N2) {
        float pn = sz[eu_r[j]] - sz[ev_r[j]];
        float yp = t_r[j] - pn;
        float t2 = yp + q_r[j];
        float yn = fmaxf(t2, 0.f);
        q_r[j] = t2 - yn;
        y_r[j] = yn;
        float tn = yn + pn;
        t_r[j] = tn;
        st[e] = tn;
      }
    }
    __syncthreads();
  }

#pragma unroll
  for (int j = 0; j < 3; ++j) {
    int e = tid + 256 * j;
    if (e < N2) out[bb * N2 + e] = y_r[j];
  }
}

extern "C" void kernel_launch(void* const* d_in, const int* in_sizes, int n_in,
                              void* d_out, int out_size, void* d_ws, size_t ws_size,
                              hipStream_t stream) {
  const float* d   = (const float*)d_in[0];
  const float* W1  = (const float*)d_in[1];
  const float* b1  = (const float*)d_in[2];
  const float* W2  = (const float*)d_in[3];
  const float* b2  = (const float*)d_in[4];
  // d_in[5] = A (structure hardcoded), d_in[6] = b_eq
  const float* beq = (const float*)d_in[6];
  float* out = (float*)d_out;
  spnet_kernel<<<NB, 256, 0, stream>>>(d, W1, b1, W2, b2, beq, out);
}

// Round 3
// 220.963 us; speedup vs baseline: 1.7293x; 1.0164x over previous
//
#include <hip/hip_runtime.h>
#include <math.h>

#define G 20
#define N1 400      // nodes
#define N2 760      // edges
#define CTXS 64
#define HID 640
#define NB 256      // batch
#define ITERS 100
#define PI_D 3.14159265358979323846

// One block per batch item.
// Grid-plane state: tR[20][20] (right-edge t, col 19 dummy=0), tD[21][20]
// (down-edge (i,j) at [i+1][j]; rows 0 and 20 stay 0). Dykstra t,q,y in regs.
// DCT chain (all stages read natural rows, V register-resident):
//   s1: T1[i][l] = sum_j R[i][j] V[l][j]        -> store T1T[l][i]
//   s2: T2'[k][l] = S[k][l] sum_i V[k][i] T1T[l][i] -> store T2T[l][k] (b128)
//   s3: W3[i][l] = sum_k V[k][i] T2T[l][k]      -> store W3[i][l] scattered
//   s4: Z[i][j]  = sum_l W3[i][l] V[l][j]       -> store Z[i][j] (b128)
// Roles: tid<100 = DCT + down-edges (waves 0-1); tid 128..227 = resid + right-edges.
__global__ __launch_bounds__(256, 1) void spnet_kernel(
    const float* __restrict__ dmat, const float* __restrict__ W1,
    const float* __restrict__ b1v, const float* __restrict__ W2,
    const float* __restrict__ b2v, const float* __restrict__ beq,
    float* __restrict__ out)
{
  const int tid = threadIdx.x;
  const int bb  = blockIdx.x;

  __shared__ __align__(16) float sV[N1];
  __shared__ __align__(16) float sdrow[CTXS];
  __shared__ __align__(16) float sh[HID];
  __shared__ __align__(16) float st0[N2];        // initial t0 = -w, edge-indexed
  __shared__ __align__(16) float tRs[G][G];
  __shared__ __align__(16) float tDs[21][G];
  __shared__ __align__(16) float srow[G][G];
  __shared__ __align__(16) float T1T[G][G];
  __shared__ __align__(16) float T2T[G][G];
  __shared__ __align__(16) float W3m[G][G];
  __shared__ __align__(16) float Zs[G][G];

  // ---------- init tables / zero planes ----------
  for (int t = tid; t < N1; t += 256) {
    int k = t / G, i = t - G * k;
    double nk = (k == 0) ? 0.22360679774997896 : 0.31622776601683794;
    sV[t] = (float)(nk * cos(PI_D * (double)(k * (2 * i + 1)) / 40.0));
    ((float*)tRs)[t] = 0.f;
  }
  for (int t = tid; t < 21 * G; t += 256) ((float*)tDs)[t] = 0.f;
  if (tid < CTXS) sdrow[tid] = dmat[bb * CTXS + tid];
  __syncthreads();

  // ---------- MLP layer 1 ----------
  if (tid < HID / 4) {
    float4 acc = *(const float4*)(b1v + 4 * tid);
#pragma unroll 4
    for (int k = 0; k < CTXS; k += 4) {
      float4 h4 = *(const float4*)(sdrow + k);
      const float* wb = W1 + k * HID + 4 * tid;
      float4 w0 = *(const float4*)(wb);
      float4 w1 = *(const float4*)(wb + HID);
      float4 w2 = *(const float4*)(wb + 2 * HID);
      float4 w3 = *(const float4*)(wb + 3 * HID);
      acc.x = fmaf(h4.x, w0.x, acc.x); acc.y = fmaf(h4.x, w0.y, acc.y);
      acc.z = fmaf(h4.x, w0.z, acc.z); acc.w = fmaf(h4.x, w0.w, acc.w);
      acc.x = fmaf(h4.y, w1.x, acc.x); acc.y = fmaf(h4.y, w1.y, acc.y);
      acc.z = fmaf(h4.y, w1.z, acc.z); acc.w = fmaf(h4.y, w1.w, acc.w);
      acc.x = fmaf(h4.z, w2.x, acc.x); acc.y = fmaf(h4.z, w2.y, acc.y);
      acc.z = fmaf(h4.z, w2.z, acc.z); acc.w = fmaf(h4.z, w2.w, acc.w);
      acc.x = fmaf(h4.w, w3.x, acc.x); acc.y = fmaf(h4.w, w3.y, acc.y);
      acc.z = fmaf(h4.w, w3.z, acc.z); acc.w = fmaf(h4.w, w3.w, acc.w);
    }
    acc.x = acc.x > 0.f ? acc.x : 0.1f * acc.x;
    acc.y = acc.y > 0.f ? acc.y : 0.1f * acc.y;
    acc.z = acc.z > 0.f ? acc.z : 0.1f * acc.z;
    acc.w = acc.w > 0.f ? acc.w : 0.1f * acc.w;
    *(float4*)(sh + 4 * tid) = acc;
  }
  __syncthreads();

  // ---------- MLP layer 2 -> st0 = -w ----------
  if (tid < N2 / 4) {
    float4 acc = *(const float4*)(b2v + 4 * tid);
#pragma unroll 2
    for (int k = 0; k < HID; k += 4) {
      float4 h4 = *(const float4*)(sh + k);
      const float* wb = W2 + k * N2 + 4 * tid;
      float4 w0 = *(const float4*)(wb);
      float4 w1 = *(const float4*)(wb + N2);
      float4 w2 = *(const float4*)(wb + 2 * N2);
      float4 w3 = *(const float4*)(wb + 3 * N2);
      acc.x = fmaf(h4.x, w0.x, acc.x); acc.y = fmaf(h4.x, w0.y, acc.y);
      acc.z = fmaf(h4.x, w0.z, acc.z); acc.w = fmaf(h4.x, w0.w, acc.w);
      acc.x = fmaf(h4.y, w1.x, acc.x); acc.y = fmaf(h4.y, w1.y, acc.y);
      acc.z = fmaf(h4.y, w1.z, acc.z); acc.w = fmaf(h4.y, w1.w, acc.w);
      acc.x = fmaf(h4.z, w2.x, acc.x); acc.y = fmaf(h4.z, w2.y, acc.y);
      acc.z = fmaf(h4.z, w2.z, acc.z); acc.w = fmaf(h4.z, w2.w, acc.w);
      acc.x = fmaf(h4.w, w3.x, acc.x); acc.y = fmaf(h4.w, w3.y, acc.y);
      acc.z = fmaf(h4.w, w3.z, acc.z); acc.w = fmaf(h4.w, w3.w, acc.w);
    }
    float4 s; s.x = -acc.x; s.y = -acc.y; s.z = -acc.z; s.w = -acc.w;
    *(float4*)(st0 + 4 * tid) = s;
  }
  __syncthreads();

  // ---------- roles ----------
  const bool isD = (tid < 100);                   // DCT + down edges
  const int  rid = tid - 128;
  const bool isR = (rid >= 0 && rid < 100);       // resid + right edges

  // DCT register state
  const int dx  = tid % G;         // data row
  const int dk0 = 4 * (tid / G);   // V-index group (valid when isD)
  float Vr[4][G], Vc[4][G], Sv[4];
  if (isD) {
#pragma unroll
    for (int a = 0; a < 4; ++a) {
      int k = dk0 + a;
#pragma unroll
      for (int m = 0; m < G; ++m) { Vr[a][m] = sV[k * G + m]; Vc[a][m] = sV[m * G + k]; }
      double lk = 2.0 - 2.0 * cos(PI_D * (double)k / 20.0);
      double lx = 2.0 - 2.0 * cos(PI_D * (double)dx / 20.0);
      Sv[a] = (k == 0 && dx == 0) ? 0.f : (float)(1.0 / (lk + lx));
    }
  }

  // down-edge state: edges (di, dj4..dj4+3), valid when di<19
  const int di = tid / 5, dj4 = (tid % 5) * 4;
  const bool dAct = isD && (di < 19);
  float dT[4], dQ[4], dY[4];
  if (dAct) {
#pragma unroll
    for (int m = 0; m < 4; ++m) {
      int j = dj4 + m;
      int e = (j < 19) ? (39 * di + 2 * j + 1) : (39 * di + 38);
      dT[m] = st0[e]; dQ[m] = 0.f; dY[m] = 0.f;
    }
    float4 w4 = {dT[0], dT[1], dT[2], dT[3]};
    *(float4*)&tDs[di + 1][dj4] = w4;
  }

  // right-edge + resid state: node row ri, cols rj4..rj4+3
  const int ri = rid / 5, rj4 = (rid % 5) * 4;
  float rT[4], rQ[4], rY[4]; float4 bq4 = {0.f, 0.f, 0.f, 0.f};
  if (isR) {
#pragma unroll
    for (int m = 0; m < 4; ++m) {
      int j = rj4 + m;
      if (j < 19) {
        int e = (ri < 19) ? (39 * ri + 2 * j) : (741 + j);
        rT[m] = st0[e];
      } else rT[m] = 0.f;
      rQ[m] = 0.f; rY[m] = 0.f;
    }
    float4 w4 = {rT[0], rT[1], rT[2], rT[3]};
    *(float4*)&tRs[ri][rj4] = w4;
    bq4 = *(const float4*)(beq + ri * G + rj4);
  }
  __syncthreads();

  // ---------- 100 Dykstra iterations ----------
  for (int it = 0; it < ITERS; ++it) {
    // resid: r[i][j] = tR[i][j]+tD[i][j] - tR[i][j-1]-tD[i-1][j] - beq
    if (isR) {
      float4 oR = *(const float4*)&tRs[ri][rj4];
      float  lf = (rj4 > 0) ? tRs[ri][rj4 - 1] : 0.f;
      float4 oD = *(const float4*)&tDs[ri + 1][rj4];
      float4 iD = *(const float4*)&tDs[ri][rj4];
      float4 r4;
      r4.x = oR.x + oD.x - lf   - iD.x - bq4.x;
      r4.y = oR.y + oD.y - oR.x - iD.y - bq4.y;
      r4.z = oR.z + oD.z - oR.y - iD.z - bq4.z;
      r4.w = oR.w + oD.w - oR.z - iD.w - bq4.w;
      *(float4*)&srow[ri][rj4] = r4;
    }
    __syncthreads();

    // s1: T1T[l][dx] = sum_j srow[dx][j] V[l][j]
    if (isD) {
      const float4* Rp = (const float4*)&srow[dx][0];
      float4 a0 = Rp[0], a1 = Rp[1], a2 = Rp[2], a3 = Rp[3], a4 = Rp[4];
      float rr[G] = {a0.x,a0.y,a0.z,a0.w, a1.x,a1.y,a1.z,a1.w, a2.x,a2.y,a2.z,a2.w,
                     a3.x,a3.y,a3.z,a3.w, a4.x,a4.y,a4.z,a4.w};
#pragma unroll
      for (int a = 0; a < 4; ++a) {
        float acc = 0.f;
#pragma unroll
        for (int m = 0; m < G; ++m) acc = fmaf(Vr[a][m], rr[m], acc);
        T1T[dk0 + a][dx] = acc;
      }
    }
    __syncthreads();

    // s2: T2T[dx][k] = S[k][dx] * sum_i V[k][i] T1T[dx][i]   (b128 write)
    if (isD) {
      const float4* Rp = (const float4*)&T1T[dx][0];
      float4 a0 = Rp[0], a1 = Rp[1], a2 = Rp[2], a3 = Rp[3], a4 = Rp[4];
      float rr[G] = {a0.x,a0.y,a0.z,a0.w, a1.x,a1.y,a1.z,a1.w, a2.x,a2.y,a2.z,a2.w,
                     a3.x,a3.y,a3.z,a3.w, a4.x,a4.y,a4.z,a4.w};
      float o[4];
#pragma unroll
      for (int a = 0; a < 4; ++a) {
        float acc = 0.f;
#pragma unroll
        for (int m = 0; m < G; ++m) acc = fmaf(Vr[a][m], rr[m], acc);
        o[a] = acc * Sv[a];
      }
      float4 w4 = {o[0], o[1], o[2], o[3]};
      *(float4*)&T2T[dx][dk0] = w4;
    }
    __syncthreads();

    // s3: W3m[i][dx] = sum_k V[k][i] T2T[dx][k]
    if (isD) {
      const float4* Rp = (const float4*)&T2T[dx][0];
      float4 a0 = Rp[0], a1 = Rp[1], a2 = Rp[2], a3 = Rp[3], a4 = Rp[4];
      float rr[G] = {a0.x,a0.y,a0.z,a0.w, a1.x,a1.y,a1.z,a1.w, a2.x,a2.y,a2.z,a2.w,
                     a3.x,a3.y,a3.z,a3.w, a4.x,a4.y,a4.z,a4.w};
#pragma unroll
      for (int a = 0; a < 4; ++a) {
        float acc = 0.f;
#pragma unroll
        for (int m = 0; m < G; ++m) acc = fmaf(Vc[a][m], rr[m], acc);
        W3m[dk0 + a][dx] = acc;
      }
    }
    __syncthreads();

    // s4: Zs[dx][j] = sum_l W3m[dx][l] V[l][j]   (b128 write)
    if (isD) {
      const float4* Rp = (const float4*)&W3m[dx][0];
      float4 a0 = Rp[0], a1 = Rp[1], a2 = Rp[2], a3 = Rp[3], a4 = Rp[4];
      float rr[G] = {a0.x,a0.y,a0.z,a0.w, a1.x,a1.y,a1.z,a1.w, a2.x,a2.y,a2.z,a2.w,
                     a3.x,a3.y,a3.z,a3.w, a4.x,a4.y,a4.z,a4.w};
      float o[4];
#pragma unroll
      for (int a = 0; a < 4; ++a) {
        float acc = 0.f;
#pragma unroll
        for (int m = 0; m < G; ++m) acc = fmaf(Vc[a][m], rr[m], acc);
        o[a] = acc;
      }
      float4 w4 = {o[0], o[1], o[2], o[3]};
      *(float4*)&Zs[dx][dk0] = w4;
    }
    __syncthreads();

    // right edges: pn = z[i][j] - z[i][j+1]
    if (isR) {
      float4 z4 = *(const float4*)&Zs[ri][rj4];
      float  zR = (rj4 < 16) ? Zs[ri][rj4 + 4] : 0.f;
      float pn[4] = {z4.x - z4.y, z4.y - z4.z, z4.z - z4.w, z4.w - zR};
      if (rj4 == 16) pn[3] = 0.f;   // dummy col stays 0
#pragma unroll
      for (int m = 0; m < 4; ++m) {
        float t2 = rT[m] - pn[m] + rQ[m];
        float yn = fmaxf(t2, 0.f);
        rQ[m] = t2 - yn; rY[m] = yn; rT[m] = yn + pn[m];
      }
      float4 w4 = {rT[0], rT[1], rT[2], rT[3]};
      *(float4*)&tRs[ri][rj4] = w4;
    }
    // down edges: pn = z[i][j] - z[i+1][j]
    if (dAct) {
      float4 z4 = *(const float4*)&Zs[di][dj4];
      float4 zb = *(const float4*)&Zs[di + 1][dj4];
      float pn[4] = {z4.x - zb.x, z4.y - zb.y, z4.z - zb.z, z4.w - zb.w};
#pragma unroll
      for (int m = 0; m < 4; ++m) {
        float t2 = dT[m] - pn[m] + dQ[m];
        float yn = fmaxf(t2, 0.f);
        dQ[m] = t2 - yn; dY[m] = yn; dT[m] = yn + pn[m];
      }
      float4 w4 = {dT[0], dT[1], dT[2], dT[3]};
      *(float4*)&tDs[di + 1][dj4] = w4;
    }
    __syncthreads();
  }

  // ---------- output ----------
  if (isR) {
#pragma unroll
    for (int m = 0; m < 4; ++m) {
      int j = rj4 + m;
      if (j < 19) {
        int e = (ri < 19) ? (39 * ri + 2 * j) : (741 + j);
        out[bb * N2 + e] = rY[m];
      }
    }
  }
  if (dAct) {
#pragma unroll
    for (int m = 0; m < 4; ++m) {
      int j = dj4 + m;
      int e = (j < 19) ? (39 * di + 2 * j + 1) : (39 * di + 38);
      out[bb * N2 + e] = dY[m];
    }
  }
}

extern "C" void kernel_launch(void* const* d_in, const int* in_sizes, int n_in,
                              void* d_out, int out_size, void* d_ws, size_t ws_size,
                              hipStream_t stream) {
  const float* d   = (const float*)d_in[0];
  const float* W1  = (const float*)d_in[1];
  const float* b1  = (const float*)d_in[2];
  const float* W2  = (const float*)d_in[3];
  const float* b2  = (const float*)d_in[4];
  const float* beq = (const float*)d_in[6];
  float* out = (float*)d_out;
  spnet_kernel<<<NB, 256, 0, stream>>>(d, W1, b1, W2, b2, beq, out);
}